// Round 6
// baseline (869.785 us; speedup 1.0000x reference)
//
#include <hip/hip_runtime.h>
#include <stdint.h>
#include <math.h>

#define N_NODES 100000
#define N_EDGES 1600000

typedef __bf16 bf16_t;
typedef __attribute__((ext_vector_type(2))) __bf16 bf16x2;
typedef __attribute__((ext_vector_type(8))) __bf16 bf16x8;
typedef __attribute__((ext_vector_type(4))) float f32x4;

__device__ __forceinline__ f32x4 mfma16(bf16x8 a, bf16x8 b, f32x4 c) {
  return __builtin_amdgcn_mfma_f32_16x16x32_bf16(a, b, c, 0, 0, 0);
}

// ---------------- Threefry-2x32 (JAX-compatible) ----------------
__device__ __host__ __forceinline__ uint32_t rotl32(uint32_t v, int d) {
  return (v << d) | (v >> (32 - d));
}

__device__ __host__ __forceinline__ void threefry2x32(uint32_t k0, uint32_t k1,
                                                      uint32_t x0, uint32_t x1,
                                                      uint32_t& o0, uint32_t& o1) {
  uint32_t ks0 = k0, ks1 = k1, ks2 = k0 ^ k1 ^ 0x1BD11BDAu;
  x0 += ks0; x1 += ks1;
#define TF_R(r) { x0 += x1; x1 = rotl32(x1, r); x1 ^= x0; }
  TF_R(13) TF_R(15) TF_R(26) TF_R(6)
  x0 += ks1; x1 += ks2 + 1u;
  TF_R(17) TF_R(29) TF_R(16) TF_R(24)
  x0 += ks2; x1 += ks0 + 2u;
  TF_R(13) TF_R(15) TF_R(26) TF_R(6)
  x0 += ks0; x1 += ks1 + 3u;
  TF_R(17) TF_R(29) TF_R(16) TF_R(24)
  x0 += ks1; x1 += ks2 + 4u;
  TF_R(13) TF_R(15) TF_R(26) TF_R(6)
  x0 += ks2; x1 += ks0 + 5u;
#undef TF_R
  o0 = x0; o1 = x1;
}

// Partitionable-threefry dropout (JAX default): bits = o0^o1 of tf(key; 0, idx)
__device__ __forceinline__ float drop_scale(uint32_t idx, uint32_t k0, uint32_t k1) {
  uint32_t o0, o1;
  threefry2x32(k0, k1, 0u, idx, o0, o1);
  uint32_t bits = o0 ^ o1;
  float u = __uint_as_float((bits >> 9) | 0x3f800000u) - 1.0f;
  return (u < 0.5f) ? 2.0f : 0.0f;
}

// ---------------- Edge dtype detect + canonicalize ----------------
__global__ __launch_bounds__(256) void detect_kernel(const int* __restrict__ ei,
                                                     int* __restrict__ found_nonzero) {
  int idx = blockIdx.x * 256 + threadIdx.x;  // 0..2047
  size_t j = (size_t)idx * 781;              // < 1.6M
  if (ei[2 * j + 1] != 0) atomicOr(found_nonzero, 1);
}

__global__ __launch_bounds__(256) void convert_kernel(const int* __restrict__ ei,
                                                      const int* __restrict__ found_nonzero,
                                                      int* __restrict__ row32,
                                                      int* __restrict__ col32) {
  int e = blockIdx.x * 256 + threadIdx.x;
  if (e >= N_EDGES) return;
  if (*found_nonzero) {  // int32 layout
    row32[e] = ei[e];
    col32[e] = ei[N_EDGES + e];
  } else {               // int64 layout: take low words
    row32[e] = ei[2 * (size_t)e];
    col32[e] = ei[2 * ((size_t)N_EDGES + (size_t)e)];
  }
}

// ---------------- Graph preprocessing ----------------
__global__ __launch_bounds__(256) void deg_kernel(const int* __restrict__ col,
                                                  int* __restrict__ deg) {
  int e = blockIdx.x * 256 + threadIdx.x;
  if (e < N_EDGES) atomicAdd(&deg[col[e]], 1);
}

__global__ __launch_bounds__(256) void dis_kernel(const int* __restrict__ deg,
                                                  float* __restrict__ dis) {
  int n = blockIdx.x * 256 + threadIdx.x;
  if (n < N_NODES) {
    int d = deg[n];
    dis[n] = (d > 0) ? (1.0f / sqrtf((float)d)) : 0.0f;
  }
}

// 3-phase parallel exclusive scan of deg -> rptr (N_NODES+1 entries)
#define SCAN_NB 391  // ceil(100000/256)
__global__ __launch_bounds__(256) void bsum_kernel(const int* __restrict__ deg,
                                                   int* __restrict__ bsum) {
  __shared__ int sh[256];
  int i = blockIdx.x * 256 + threadIdx.x;
  sh[threadIdx.x] = (i < N_NODES) ? deg[i] : 0;
  __syncthreads();
  for (int ofs = 128; ofs > 0; ofs >>= 1) {
    if (threadIdx.x < ofs) sh[threadIdx.x] += sh[threadIdx.x + ofs];
    __syncthreads();
  }
  if (threadIdx.x == 0) bsum[blockIdx.x] = sh[0];
}

__global__ __launch_bounds__(512) void bscan_kernel(const int* __restrict__ bsum,
                                                    int* __restrict__ boffs) {
  __shared__ int sh[512];
  int t = threadIdx.x;
  int v = (t < SCAN_NB) ? bsum[t] : 0;
  sh[t] = v;
  __syncthreads();
  for (int ofs = 1; ofs < 512; ofs <<= 1) {
    int u = (t >= ofs) ? sh[t - ofs] : 0;
    __syncthreads();
    sh[t] += u;
    __syncthreads();
  }
  if (t < SCAN_NB) boffs[t] = sh[t] - v;  // exclusive
  if (t == 0) boffs[SCAN_NB] = sh[SCAN_NB - 1];
}

__global__ __launch_bounds__(256) void rptr_kernel(const int* __restrict__ deg,
                                                   const int* __restrict__ boffs,
                                                   int* __restrict__ rptr) {
  __shared__ int sh[256];
  int i = blockIdx.x * 256 + threadIdx.x;
  int v = (i < N_NODES) ? deg[i] : 0;
  sh[threadIdx.x] = v;
  __syncthreads();
  for (int ofs = 1; ofs < 256; ofs <<= 1) {
    int u = (threadIdx.x >= ofs) ? sh[threadIdx.x - ofs] : 0;
    __syncthreads();
    sh[threadIdx.x] += u;
    __syncthreads();
  }
  if (i <= N_NODES) rptr[i] = boffs[blockIdx.x] + sh[threadIdx.x] - v;
}

__global__ __launch_bounds__(256) void fill_kernel(const int* __restrict__ row,
                                                   const int* __restrict__ col,
                                                   const float* __restrict__ dis,
                                                   const int* __restrict__ rptr,
                                                   int* cursor,
                                                   int* __restrict__ erow,
                                                   float* __restrict__ enorm) {
  int e = blockIdx.x * 256 + threadIdx.x;
  if (e < N_EDGES) {
    int c = col[e], r = row[e];
    int p = atomicAdd(&cursor[c], 1);
    int idx = rptr[c] + p;
    erow[idx] = r;
    enorm[idx] = dis[r] * dis[c];
  }
}

// ---------------- Weight pre-conversion f32 -> bf16 ----------------
__global__ __launch_bounds__(256) void wcvt_kernel(
    const float* __restrict__ W1, const float* __restrict__ W2,
    const float* __restrict__ W3,
    bf16_t* __restrict__ Wb1, bf16_t* __restrict__ Wb2,
    bf16_t* __restrict__ Wb3) {
  int i = blockIdx.x * 256 + threadIdx.x;
  if (i < 65536) Wb1[i] = (bf16_t)W1[i];
  if (i < 32768) Wb2[i] = (bf16_t)W2[i];
  if (i < 4096)  Wb3[i] = (bf16_t)W3[i];
}

// ---------------- MFMA matmul: y_k = h @ W_k^T (+bias into y0) ----------------
// A = hi+lo bf16 split (exact), W bf16. A-frags hoisted to registers once;
// B double-buffered in the (freed) A-staging LDS, staging pipelined with MFMA.
// AHL: A given as pre-split bf16 hi/lo arrays; else f32 (split in-kernel).
// YB: y1..y3 emitted bf16; y0 always f32 (carries bias).
template <int DIN, int LOG_DOUT, int NCH, bool YB, bool AHL>
__global__ __launch_bounds__(256) void matmul_mfma_kernel(
    const void* __restrict__ hA, const void* __restrict__ hAlo,
    const bf16_t* __restrict__ Wb, const float* __restrict__ bias,
    float* __restrict__ y0, void* __restrict__ y1,
    void* __restrict__ y2, void* __restrict__ y3) {
  constexpr int LDK = DIN + 8;
  constexpr int DOUT = 1 << LOG_DOUT;
  constexpr int KI = DIN / 32;
  __shared__ bf16_t sm[2][64 * LDK];  // A hi/lo staging -> B double-buffer
  const int m0 = blockIdx.x * 64;
  const int tid = threadIdx.x;

  // ---- Stage A tile: hi -> sm[0], lo -> sm[1] ----
  if (AHL) {
    constexpr int NL = 64 * DIN / 8 / 256;  // uint4 = 8 bf16
#pragma unroll
    for (int it = 0; it < NL; ++it) {
      int idx = tid + it * 256;
      int r = idx / (DIN / 8), cc = (idx % (DIN / 8)) * 8;
      int gm = m0 + r;
      uint4 vh = make_uint4(0, 0, 0, 0), vl = make_uint4(0, 0, 0, 0);
      if (gm < N_NODES) {
        vh = ((const uint4*)hA)[((size_t)gm * DIN + cc) >> 3];
        vl = ((const uint4*)hAlo)[((size_t)gm * DIN + cc) >> 3];
      }
      *(uint4*)&sm[0][r * LDK + cc] = vh;
      *(uint4*)&sm[1][r * LDK + cc] = vl;
    }
  } else {
    constexpr int NL = 64 * DIN / 4 / 256;
    union U4 { bf16_t b[4]; uint2 u; };
#pragma unroll
    for (int it = 0; it < NL; ++it) {
      int idx = tid + it * 256;
      int r = idx / (DIN / 4), cc = (idx % (DIN / 4)) * 4;
      int gm = m0 + r;
      float4 v = (gm < N_NODES) ? ((const float4*)hA)[((size_t)gm * DIN + cc) >> 2]
                                : make_float4(0.f, 0.f, 0.f, 0.f);
      U4 hi, lo;
      hi.b[0] = (bf16_t)v.x; lo.b[0] = (bf16_t)(v.x - (float)hi.b[0]);
      hi.b[1] = (bf16_t)v.y; lo.b[1] = (bf16_t)(v.y - (float)hi.b[1]);
      hi.b[2] = (bf16_t)v.z; lo.b[2] = (bf16_t)(v.z - (float)hi.b[2]);
      hi.b[3] = (bf16_t)v.w; lo.b[3] = (bf16_t)(v.w - (float)hi.b[3]);
      *(uint2*)&sm[0][r * LDK + cc] = hi.u;
      *(uint2*)&sm[1][r * LDK + cc] = lo.u;
    }
  }
  __syncthreads();

  const int w = tid >> 6, lane = tid & 63;
  const int wm = w & 1, wn = w >> 1;
  const int quad = lane >> 4, lr = lane & 15;

  // ---- Hoist A fragments to registers (read LDS once) ----
  bf16x8 aH[2][KI], aL[2][KI];
#pragma unroll
  for (int mt = 0; mt < 2; ++mt)
#pragma unroll
    for (int ki = 0; ki < KI; ++ki) {
      int rowa = wm * 32 + mt * 16 + lr;
      int koff = ki * 32 + quad * 8;
      aH[mt][ki] = *(const bf16x8*)&sm[0][rowa * LDK + koff];
      aL[mt][ki] = *(const bf16x8*)&sm[1][rowa * LDK + koff];
    }
  __syncthreads();  // A staging LDS now free for B double-buffer

  constexpr int NLB = 64 * DIN / 8 / 256;  // uint4 loads of bf16 W
  uint4 wreg[NLB];
#pragma unroll
  for (int it = 0; it < NLB; ++it) {
    int idx = tid + it * 256;
    int r = idx / (DIN / 8), cc = (idx % (DIN / 8)) * 8;
    wreg[it] = ((const uint4*)Wb)[(((size_t)r) * DIN + cc) >> 3];
    *(uint4*)&sm[0][r * LDK + cc] = wreg[it];
  }
  __syncthreads();

  for (int nc = 0; nc < NCH; ++nc) {
    int p = nc & 1;
    if (nc + 1 < NCH) {
#pragma unroll
      for (int it = 0; it < NLB; ++it) {
        int idx = tid + it * 256;
        int r = idx / (DIN / 8), cc = (idx % (DIN / 8)) * 8;
        wreg[it] = ((const uint4*)Wb)[(((size_t)((nc + 1) * 64 + r)) * DIN + cc) >> 3];
      }
    }

    f32x4 acc[2][2] = {};
#pragma unroll
    for (int ki = 0; ki < KI; ++ki) {
      int koff = ki * 32 + quad * 8;
      bf16x8 bfr[2];
#pragma unroll
      for (int nt = 0; nt < 2; ++nt)
        bfr[nt] = *(const bf16x8*)&sm[p][(wn * 32 + nt * 16 + lr) * LDK + koff];
#pragma unroll
      for (int mt = 0; mt < 2; ++mt)
#pragma unroll
        for (int nt = 0; nt < 2; ++nt) {
          acc[mt][nt] = mfma16(aH[mt][ki], bfr[nt], acc[mt][nt]);
          acc[mt][nt] = mfma16(aL[mt][ki], bfr[nt], acc[mt][nt]);
        }
    }

    if (nc + 1 < NCH) {
#pragma unroll
      for (int it = 0; it < NLB; ++it) {
        int idx = tid + it * 256;
        int r = idx / (DIN / 8), cc = (idx % (DIN / 8)) * 8;
        *(uint4*)&sm[p ^ 1][r * LDK + cc] = wreg[it];
      }
    }
    __syncthreads();

    // ---- Epilogue chunk nc: D[row=quad*4+r][col=lr] ----
    const int n0 = nc * 64;
#pragma unroll
    for (int mt = 0; mt < 2; ++mt)
#pragma unroll
      for (int nt = 0; nt < 2; ++nt) {
        int ng = n0 + wn * 32 + nt * 16 + lr;
        int k = ng >> LOG_DOUT;
        int o = ng & (DOUT - 1);
        float badd = (k == 0) ? bias[o] : 0.f;
#pragma unroll
        for (int r = 0; r < 4; ++r) {
          int m = m0 + wm * 32 + mt * 16 + quad * 4 + r;
          if (m >= N_NODES) continue;
          float val = acc[mt][nt][r] + badd;
          size_t oi = (size_t)m * DOUT + o;
          if (k == 0) {
            y0[oi] = val;
          } else {
            void* yk = (k == 1) ? y1 : (k == 2) ? y2 : y3;
            if (YB) ((bf16_t*)yk)[oi] = (bf16_t)val;
            else    ((float*)yk)[oi]  = val;
          }
        }
      }
  }
}

// ---------------- Propagation: out[c] = sum_e norm*z[row_e] + add[c] ----------
// 2 features per lane. ZBF/ABF: z / add in bf16.
// OMODE: 0 = f32 out, 1 = bf16 out, 2 = bf16 hi/lo pair (outv = hi, outv2 = lo)
// EPI: 0 = none, 1 = dropout(key1), 2 = elu then dropout(key2)
template <int D, int EPI, bool ZBF, bool ABF, int OMODE>
__global__ __launch_bounds__(256) void prop_kernel(
    const void* __restrict__ zv, const void* __restrict__ addv,
    void* __restrict__ outv, void* __restrict__ outv2,
    const int* __restrict__ rptr, const int* __restrict__ erow,
    const float* __restrict__ enorm,
    uint32_t k0, uint32_t k1) {
  constexpr int LPN = D / 2;        // lanes per node (2 feats/lane)
  constexpr int NPB = 256 / LPN;    // nodes per block
  int lane = threadIdx.x % LPN;
  int nsub = threadIdx.x / LPN;
  int c = blockIdx.x * NPB + nsub;
  if (c >= N_NODES) return;
  int e0 = rptr[c], e1 = rptr[c + 1];
  float a0 = 0.f, a1 = 0.f;

  auto ld = [&](int r) -> float2 {
    if (ZBF) {
      bf16x2 v = ((const bf16x2*)zv)[(size_t)r * LPN + lane];
      return make_float2((float)v.x, (float)v.y);
    } else {
      return ((const float2*)zv)[(size_t)r * LPN + lane];
    }
  };

  int e = e0;
  for (; e + 3 < e1; e += 4) {
    int r0 = erow[e], r1 = erow[e + 1], r2 = erow[e + 2], r3 = erow[e + 3];
    float w0 = enorm[e], w1 = enorm[e + 1], w2 = enorm[e + 2], w3 = enorm[e + 3];
    float2 v0 = ld(r0), v1 = ld(r1), v2 = ld(r2), v3 = ld(r3);
    a0 = fmaf(w0, v0.x, a0); a1 = fmaf(w0, v0.y, a1);
    a0 = fmaf(w1, v1.x, a0); a1 = fmaf(w1, v1.y, a1);
    a0 = fmaf(w2, v2.x, a0); a1 = fmaf(w2, v2.y, a1);
    a0 = fmaf(w3, v3.x, a0); a1 = fmaf(w3, v3.y, a1);
  }
  for (; e < e1; ++e) {
    float wv = enorm[e];
    float2 v = ld(erow[e]);
    a0 = fmaf(wv, v.x, a0); a1 = fmaf(wv, v.y, a1);
  }

  size_t pidx = (size_t)c * LPN + lane;
  uint32_t fidx = (uint32_t)c * D + 2 * lane;
  float ax, ay;
  if (ABF) {
    bf16x2 av = ((const bf16x2*)addv)[pidx];
    ax = (float)av.x; ay = (float)av.y;
  } else {
    float2 av = ((const float2*)addv)[pidx];
    ax = av.x; ay = av.y;
  }
  float o0 = a0 + ax, o1 = a1 + ay;
  if (EPI == 1) {
    o0 *= drop_scale(fidx, k0, k1);
    o1 *= drop_scale(fidx + 1, k0, k1);
  }
  if (EPI == 2) {
    o0 = (o0 > 0.f) ? o0 : expm1f(o0);
    o1 = (o1 > 0.f) ? o1 : expm1f(o1);
    o0 *= drop_scale(fidx, k0, k1);
    o1 *= drop_scale(fidx + 1, k0, k1);
  }
  if (OMODE == 0) {
    ((float2*)outv)[pidx] = make_float2(o0, o1);
  } else if (OMODE == 1) {
    bf16x2 bv; bv.x = (bf16_t)o0; bv.y = (bf16_t)o1;
    ((bf16x2*)outv)[pidx] = bv;
  } else {
    bf16x2 hv, lv;
    hv.x = (bf16_t)o0; hv.y = (bf16_t)o1;
    lv.x = (bf16_t)(o0 - (float)hv.x);
    lv.y = (bf16_t)(o1 - (float)hv.y);
    ((bf16x2*)outv)[pidx] = hv;
    ((bf16x2*)outv2)[pidx] = lv;
  }
}

// ---------------- Launch ----------------
extern "C" void kernel_launch(void* const* d_in, const int* in_sizes, int n_in,
                              void* d_out, int out_size, void* d_ws, size_t ws_size,
                              hipStream_t stream) {
  const float* x  = (const float*)d_in[0];
  const int*   ei = (const int*)d_in[1];
  const float* W1 = (const float*)d_in[2];
  const float* b1 = (const float*)d_in[3];
  const float* W2 = (const float*)d_in[4];
  const float* b2 = (const float*)d_in[5];
  const float* W3 = (const float*)d_in[6];
  const float* b3 = (const float*)d_in[7];
  float* out = (float*)d_out;

  char* ws = (char*)d_ws;
  size_t off = 0;
  auto alloc = [&](size_t bytes) -> char* {
    char* p = ws + off;
    off += (bytes + 255) & ~(size_t)255;
    return p;
  };
  int*   flag   = (int*)alloc(256);
  int*   deg    = (int*)alloc((size_t)N_NODES * 4);
  int*   cursor = (int*)alloc((size_t)N_NODES * 4);
  float* dis    = (float*)alloc((size_t)N_NODES * 4);
  int*   rptr   = (int*)alloc((size_t)(N_NODES + 1) * 4);
  int*   bsum   = (int*)alloc((size_t)(SCAN_NB + 1) * 4);
  int*   boffs  = (int*)alloc((size_t)(SCAN_NB + 1) * 4);
  int*   row32  = (int*)alloc((size_t)N_EDGES * 4);
  int*   col32  = (int*)alloc((size_t)N_EDGES * 4);
  int*   erow   = (int*)alloc((size_t)N_EDGES * 4);
  float* enorm  = (float*)alloc((size_t)N_EDGES * 4);
  bf16_t* Wb1  = (bf16_t*)alloc(65536 * 2);
  bf16_t* Wb2  = (bf16_t*)alloc(32768 * 2);
  bf16_t* Wb3  = (bf16_t*)alloc(4096 * 2);
  float*  R0  = (float*)alloc((size_t)N_NODES * 128 * 4);  // L1 y0/out; L2 y0 (f32 64)
  float*  R2  = (float*)alloc((size_t)N_NODES * 64 * 4);   // L3 z0..z3 (f32 16 x4)
  bf16_t* Zb0 = (bf16_t*)alloc((size_t)N_NODES * 128 * 2);
  bf16_t* Zb1 = (bf16_t*)alloc((size_t)N_NODES * 128 * 2);
  bf16_t* Bb1 = (bf16_t*)alloc((size_t)N_NODES * 128 * 2);
  bf16_t* Bb2 = (bf16_t*)alloc((size_t)N_NODES * 128 * 2);

  hipMemsetAsync(flag, 0, 256, stream);
  hipMemsetAsync(deg, 0, (size_t)N_NODES * 4, stream);
  hipMemsetAsync(cursor, 0, (size_t)N_NODES * 4, stream);

  detect_kernel<<<8, 256, 0, stream>>>(ei, flag);
  convert_kernel<<<(N_EDGES + 255) / 256, 256, 0, stream>>>(ei, flag, row32, col32);
  deg_kernel<<<(N_EDGES + 255) / 256, 256, 0, stream>>>(col32, deg);
  dis_kernel<<<(N_NODES + 255) / 256, 256, 0, stream>>>(deg, dis);
  bsum_kernel<<<SCAN_NB, 256, 0, stream>>>(deg, bsum);
  bscan_kernel<<<1, 512, 0, stream>>>(bsum, boffs);
  rptr_kernel<<<SCAN_NB, 256, 0, stream>>>(deg, boffs, rptr);
  fill_kernel<<<(N_EDGES + 255) / 256, 256, 0, stream>>>(row32, col32, dis, rptr,
                                                         cursor, erow, enorm);
  wcvt_kernel<<<256, 256, 0, stream>>>(W1, W2, W3, Wb1, Wb2, Wb3);

  // JAX partitionable split of key(42)=(0,42): subkey_i = threefry(key; 0, i)
  uint32_t d10, d11, d20, d21;
  threefry2x32(0u, 42u, 0u, 0u, d10, d11);  // dk1
  threefry2x32(0u, 42u, 0u, 1u, d20, d21);  // dk2

  const int MB = (N_NODES + 63) / 64;       // 1563
  const int PB4  = (N_NODES + 3) / 4;       // D=128 (NPB=4)
  const int PB8  = (N_NODES + 7) / 8;       // D=64  (NPB=8)
  const int PB32 = (N_NODES + 31) / 32;     // D=16  (NPB=32)

  // ---- Layer 1 (128 -> 128): Horner out = A(A(A y3 + y2) + y1) + y0 ; dropout1
  matmul_mfma_kernel<128, 7, 8, true, false><<<MB, 256, 0, stream>>>(
      x, nullptr, Wb1, b1, R0, Bb1, Bb2, Zb0);
  prop_kernel<128, 0, true, true, 1><<<PB4, 256, 0, stream>>>(
      Zb0, Bb2, Zb1, nullptr, rptr, erow, enorm, 0, 0);
  prop_kernel<128, 0, true, true, 1><<<PB4, 256, 0, stream>>>(
      Zb1, Bb1, Zb0, nullptr, rptr, erow, enorm, 0, 0);
  // final hop: dropout, emit hi/lo bf16 pair for layer-2 A (Ah0=Bb2, Al0=Bb1)
  prop_kernel<128, 1, true, false, 2><<<PB4, 256, 0, stream>>>(
      Zb0, R0, Bb2, Bb1, rptr, erow, enorm, d10, d11);

  // ---- Layer 2 (128 -> 64): A = (Bb2, Bb1) hi/lo; epilogue: elu + dropout2
  float*  R1f = R0;                                   // f32 64 (R0 dead)
  bf16_t* S0 = Zb0;                                   // bf16 64 slots (12.8 MB)
  bf16_t* S1 = Zb0 + (size_t)N_NODES * 64;
  bf16_t* S2 = Zb1;
  bf16_t* S3 = Zb1 + (size_t)N_NODES * 64;
  matmul_mfma_kernel<128, 6, 4, true, true><<<MB, 256, 0, stream>>>(
      Bb2, Bb1, Wb2, b2, R1f, S2, S3, S0);
  prop_kernel<64, 0, true, true, 1><<<PB8, 256, 0, stream>>>(
      S0, S3, S1, nullptr, rptr, erow, enorm, 0, 0);
  prop_kernel<64, 0, true, true, 1><<<PB8, 256, 0, stream>>>(
      S1, S2, S0, nullptr, rptr, erow, enorm, 0, 0);
  // final hop: elu+dropout, emit hi/lo for layer-3 A (Ah1=S2, Al1=S3)
  prop_kernel<64, 2, true, false, 2><<<PB8, 256, 0, stream>>>(
      S0, R1f, S2, S3, rptr, erow, enorm, d20, d21);

  // ---- Layer 3 (64 -> 16): A = (S2, S3) hi/lo; final hop writes d_out (f32)
  float* z0 = R2;
  float* z1 = R2 + (size_t)N_NODES * 16;
  float* z2 = R2 + (size_t)N_NODES * 32;
  float* z3 = R2 + (size_t)N_NODES * 48;
  matmul_mfma_kernel<64, 4, 1, false, true><<<MB, 256, 0, stream>>>(
      S2, S3, Wb3, b3, z0, z1, z2, z3);
  prop_kernel<16, 0, false, false, 0><<<PB32, 256, 0, stream>>>(
      z3, z2, z2, nullptr, rptr, erow, enorm, 0, 0);
  prop_kernel<16, 0, false, false, 0><<<PB32, 256, 0, stream>>>(
      z2, z1, z1, nullptr, rptr, erow, enorm, 0, 0);
  prop_kernel<16, 0, false, false, 0><<<PB32, 256, 0, stream>>>(
      z1, z0, out, nullptr, rptr, erow, enorm, 0, 0);

  (void)in_sizes; (void)n_in; (void)out_size; (void)ws_size;
}

// Round 7
// 831.208 us; speedup vs baseline: 1.0464x; 1.0464x over previous
//
#include <hip/hip_runtime.h>
#include <stdint.h>
#include <math.h>

#define N_NODES 100000
#define N_EDGES 1600000

typedef __bf16 bf16_t;
typedef __attribute__((ext_vector_type(2))) __bf16 bf16x2;
typedef __attribute__((ext_vector_type(8))) __bf16 bf16x8;
typedef __attribute__((ext_vector_type(4))) float f32x4;

__device__ __forceinline__ f32x4 mfma16(bf16x8 a, bf16x8 b, f32x4 c) {
  return __builtin_amdgcn_mfma_f32_16x16x32_bf16(a, b, c, 0, 0, 0);
}

// ---------------- Threefry-2x32 (JAX-compatible) ----------------
__device__ __host__ __forceinline__ uint32_t rotl32(uint32_t v, int d) {
  return (v << d) | (v >> (32 - d));
}

__device__ __host__ __forceinline__ void threefry2x32(uint32_t k0, uint32_t k1,
                                                      uint32_t x0, uint32_t x1,
                                                      uint32_t& o0, uint32_t& o1) {
  uint32_t ks0 = k0, ks1 = k1, ks2 = k0 ^ k1 ^ 0x1BD11BDAu;
  x0 += ks0; x1 += ks1;
#define TF_R(r) { x0 += x1; x1 = rotl32(x1, r); x1 ^= x0; }
  TF_R(13) TF_R(15) TF_R(26) TF_R(6)
  x0 += ks1; x1 += ks2 + 1u;
  TF_R(17) TF_R(29) TF_R(16) TF_R(24)
  x0 += ks2; x1 += ks0 + 2u;
  TF_R(13) TF_R(15) TF_R(26) TF_R(6)
  x0 += ks0; x1 += ks1 + 3u;
  TF_R(17) TF_R(29) TF_R(16) TF_R(24)
  x0 += ks1; x1 += ks2 + 4u;
  TF_R(13) TF_R(15) TF_R(26) TF_R(6)
  x0 += ks2; x1 += ks0 + 5u;
#undef TF_R
  o0 = x0; o1 = x1;
}

// Partitionable-threefry dropout (JAX default): bits = o0^o1 of tf(key; 0, idx)
__device__ __forceinline__ float drop_scale(uint32_t idx, uint32_t k0, uint32_t k1) {
  uint32_t o0, o1;
  threefry2x32(k0, k1, 0u, idx, o0, o1);
  uint32_t bits = o0 ^ o1;
  float u = __uint_as_float((bits >> 9) | 0x3f800000u) - 1.0f;
  return (u < 0.5f) ? 2.0f : 0.0f;
}

// ---------------- Edge dtype detect ----------------
// int64 layout: odd words of first half (row) are zero high-words.
__global__ __launch_bounds__(256) void detect_kernel(const int* __restrict__ ei,
                                                     int* __restrict__ found_nonzero) {
  int idx = blockIdx.x * 256 + threadIdx.x;  // 0..2047
  size_t j = (size_t)idx * 781;              // < 1.6M
  if (ei[2 * j + 1] != 0) atomicOr(found_nonzero, 1);
}

__device__ __forceinline__ int edge_row(const int* ei, bool i32, int e) {
  return i32 ? ei[e] : ei[2 * (size_t)e];
}
__device__ __forceinline__ int edge_col(const int* ei, bool i32, int e) {
  return i32 ? ei[N_EDGES + e] : ei[2 * ((size_t)N_EDGES + (size_t)e)];
}

// ---------------- Graph preprocessing ----------------
__global__ __launch_bounds__(256) void deg_kernel(const int* __restrict__ ei,
                                                  const int* __restrict__ flag,
                                                  int* __restrict__ deg) {
  int e = blockIdx.x * 256 + threadIdx.x;
  if (e < N_EDGES) {
    bool i32 = *flag != 0;
    atomicAdd(&deg[edge_col(ei, i32, e)], 1);
  }
}

__global__ __launch_bounds__(256) void dis_kernel(const int* __restrict__ deg,
                                                  float* __restrict__ dis) {
  int n = blockIdx.x * 256 + threadIdx.x;
  if (n < N_NODES) {
    int d = deg[n];
    dis[n] = (d > 0) ? (1.0f / sqrtf((float)d)) : 0.0f;
  }
}

// 3-phase parallel exclusive scan of deg -> rptr (N_NODES+1 entries)
#define SCAN_NB 391  // ceil(100000/256)
__global__ __launch_bounds__(256) void bsum_kernel(const int* __restrict__ deg,
                                                   int* __restrict__ bsum) {
  __shared__ int sh[256];
  int i = blockIdx.x * 256 + threadIdx.x;
  sh[threadIdx.x] = (i < N_NODES) ? deg[i] : 0;
  __syncthreads();
  for (int ofs = 128; ofs > 0; ofs >>= 1) {
    if (threadIdx.x < ofs) sh[threadIdx.x] += sh[threadIdx.x + ofs];
    __syncthreads();
  }
  if (threadIdx.x == 0) bsum[blockIdx.x] = sh[0];
}

__global__ __launch_bounds__(512) void bscan_kernel(const int* __restrict__ bsum,
                                                    int* __restrict__ boffs) {
  __shared__ int sh[512];
  int t = threadIdx.x;
  int v = (t < SCAN_NB) ? bsum[t] : 0;
  sh[t] = v;
  __syncthreads();
  for (int ofs = 1; ofs < 512; ofs <<= 1) {
    int u = (t >= ofs) ? sh[t - ofs] : 0;
    __syncthreads();
    sh[t] += u;
    __syncthreads();
  }
  if (t < SCAN_NB) boffs[t] = sh[t] - v;  // exclusive
  if (t == 0) boffs[SCAN_NB] = sh[SCAN_NB - 1];
}

__global__ __launch_bounds__(256) void rptr_kernel(const int* __restrict__ deg,
                                                   const int* __restrict__ boffs,
                                                   int* __restrict__ rptr) {
  __shared__ int sh[256];
  int i = blockIdx.x * 256 + threadIdx.x;
  int v = (i < N_NODES) ? deg[i] : 0;
  sh[threadIdx.x] = v;
  __syncthreads();
  for (int ofs = 1; ofs < 256; ofs <<= 1) {
    int u = (threadIdx.x >= ofs) ? sh[threadIdx.x - ofs] : 0;
    __syncthreads();
    sh[threadIdx.x] += u;
    __syncthreads();
  }
  if (i <= N_NODES) rptr[i] = boffs[blockIdx.x] + sh[threadIdx.x] - v;
}

// One packed 8B record per edge: {row, bitcast(norm)} — single scatter line.
__global__ __launch_bounds__(256) void fill_kernel(const int* __restrict__ ei,
                                                   const int* __restrict__ flag,
                                                   const float* __restrict__ dis,
                                                   const int* __restrict__ rptr,
                                                   int* cursor,
                                                   int2* __restrict__ erec) {
  int e = blockIdx.x * 256 + threadIdx.x;
  if (e < N_EDGES) {
    bool i32 = *flag != 0;
    int r = edge_row(ei, i32, e);
    int c = edge_col(ei, i32, e);
    int p = atomicAdd(&cursor[c], 1);
    int idx = rptr[c] + p;
    float nrm = dis[r] * dis[c];
    erec[idx] = make_int2(r, __float_as_int(nrm));
  }
}

// ---------------- Weight pre-conversion f32 -> bf16 ----------------
__global__ __launch_bounds__(256) void wcvt_kernel(
    const float* __restrict__ W1, const float* __restrict__ W2,
    const float* __restrict__ W3,
    bf16_t* __restrict__ Wb1, bf16_t* __restrict__ Wb2,
    bf16_t* __restrict__ Wb3) {
  int i = blockIdx.x * 256 + threadIdx.x;
  if (i < 65536) Wb1[i] = (bf16_t)W1[i];
  if (i < 32768) Wb2[i] = (bf16_t)W2[i];
  if (i < 4096)  Wb3[i] = (bf16_t)W3[i];
}

// ---------------- MFMA matmul: y_k = h @ W_k^T (+bias into y0) ----------------
// A = hi+lo bf16 split (exact), W bf16. A-frags hoisted to registers once;
// B double-buffered in the freed A-staging LDS, staging pipelined with MFMA.
// AHL: A given as pre-split bf16 hi/lo arrays; else f32 (split in-kernel).
// YB: y1..y3 emitted bf16; y0 always f32 (carries bias).
template <int DIN, int LOG_DOUT, int NCH, bool YB, bool AHL>
__global__ __launch_bounds__(256) void matmul_mfma_kernel(
    const void* __restrict__ hA, const void* __restrict__ hAlo,
    const bf16_t* __restrict__ Wb, const float* __restrict__ bias,
    float* __restrict__ y0, void* __restrict__ y1,
    void* __restrict__ y2, void* __restrict__ y3) {
  constexpr int LDK = DIN + 8;
  constexpr int DOUT = 1 << LOG_DOUT;
  constexpr int KI = DIN / 32;
  __shared__ bf16_t sm[2][64 * LDK];  // A hi/lo staging -> B double-buffer
  const int m0 = blockIdx.x * 64;
  const int tid = threadIdx.x;

  // ---- Stage A tile: hi -> sm[0], lo -> sm[1] ----
  if (AHL) {
    constexpr int NL = 64 * DIN / 8 / 256;  // uint4 = 8 bf16
#pragma unroll
    for (int it = 0; it < NL; ++it) {
      int idx = tid + it * 256;
      int r = idx / (DIN / 8), cc = (idx % (DIN / 8)) * 8;
      int gm = m0 + r;
      uint4 vh = make_uint4(0, 0, 0, 0), vl = make_uint4(0, 0, 0, 0);
      if (gm < N_NODES) {
        vh = ((const uint4*)hA)[((size_t)gm * DIN + cc) >> 3];
        vl = ((const uint4*)hAlo)[((size_t)gm * DIN + cc) >> 3];
      }
      *(uint4*)&sm[0][r * LDK + cc] = vh;
      *(uint4*)&sm[1][r * LDK + cc] = vl;
    }
  } else {
    constexpr int NL = 64 * DIN / 4 / 256;
    union U4 { bf16_t b[4]; uint2 u; };
#pragma unroll
    for (int it = 0; it < NL; ++it) {
      int idx = tid + it * 256;
      int r = idx / (DIN / 4), cc = (idx % (DIN / 4)) * 4;
      int gm = m0 + r;
      float4 v = (gm < N_NODES) ? ((const float4*)hA)[((size_t)gm * DIN + cc) >> 2]
                                : make_float4(0.f, 0.f, 0.f, 0.f);
      U4 hi, lo;
      hi.b[0] = (bf16_t)v.x; lo.b[0] = (bf16_t)(v.x - (float)hi.b[0]);
      hi.b[1] = (bf16_t)v.y; lo.b[1] = (bf16_t)(v.y - (float)hi.b[1]);
      hi.b[2] = (bf16_t)v.z; lo.b[2] = (bf16_t)(v.z - (float)hi.b[2]);
      hi.b[3] = (bf16_t)v.w; lo.b[3] = (bf16_t)(v.w - (float)hi.b[3]);
      *(uint2*)&sm[0][r * LDK + cc] = hi.u;
      *(uint2*)&sm[1][r * LDK + cc] = lo.u;
    }
  }
  __syncthreads();

  const int w = tid >> 6, lane = tid & 63;
  const int wm = w & 1, wn = w >> 1;
  const int quad = lane >> 4, lr = lane & 15;

  // ---- Hoist A fragments to registers (read LDS once) ----
  bf16x8 aH[2][KI], aL[2][KI];
#pragma unroll
  for (int mt = 0; mt < 2; ++mt)
#pragma unroll
    for (int ki = 0; ki < KI; ++ki) {
      int rowa = wm * 32 + mt * 16 + lr;
      int koff = ki * 32 + quad * 8;
      aH[mt][ki] = *(const bf16x8*)&sm[0][rowa * LDK + koff];
      aL[mt][ki] = *(const bf16x8*)&sm[1][rowa * LDK + koff];
    }
  __syncthreads();  // A staging LDS now free for B double-buffer

  constexpr int NLB = 64 * DIN / 8 / 256;  // uint4 loads of bf16 W
  uint4 wreg[NLB];
#pragma unroll
  for (int it = 0; it < NLB; ++it) {
    int idx = tid + it * 256;
    int r = idx / (DIN / 8), cc = (idx % (DIN / 8)) * 8;
    wreg[it] = ((const uint4*)Wb)[(((size_t)r) * DIN + cc) >> 3];
    *(uint4*)&sm[0][r * LDK + cc] = wreg[it];
  }
  __syncthreads();

  for (int nc = 0; nc < NCH; ++nc) {
    int p = nc & 1;
    if (nc + 1 < NCH) {
#pragma unroll
      for (int it = 0; it < NLB; ++it) {
        int idx = tid + it * 256;
        int r = idx / (DIN / 8), cc = (idx % (DIN / 8)) * 8;
        wreg[it] = ((const uint4*)Wb)[(((size_t)((nc + 1) * 64 + r)) * DIN + cc) >> 3];
      }
    }

    f32x4 acc[2][2] = {};
#pragma unroll
    for (int ki = 0; ki < KI; ++ki) {
      int koff = ki * 32 + quad * 8;
      bf16x8 bfr[2];
#pragma unroll
      for (int nt = 0; nt < 2; ++nt)
        bfr[nt] = *(const bf16x8*)&sm[p][(wn * 32 + nt * 16 + lr) * LDK + koff];
#pragma unroll
      for (int mt = 0; mt < 2; ++mt)
#pragma unroll
        for (int nt = 0; nt < 2; ++nt) {
          acc[mt][nt] = mfma16(aH[mt][ki], bfr[nt], acc[mt][nt]);
          acc[mt][nt] = mfma16(aL[mt][ki], bfr[nt], acc[mt][nt]);
        }
    }

    if (nc + 1 < NCH) {
#pragma unroll
      for (int it = 0; it < NLB; ++it) {
        int idx = tid + it * 256;
        int r = idx / (DIN / 8), cc = (idx % (DIN / 8)) * 8;
        *(uint4*)&sm[p ^ 1][r * LDK + cc] = wreg[it];
      }
    }
    __syncthreads();

    // ---- Epilogue chunk nc: D[row=quad*4+r][col=lr] ----
    const int n0 = nc * 64;
#pragma unroll
    for (int mt = 0; mt < 2; ++mt)
#pragma unroll
      for (int nt = 0; nt < 2; ++nt) {
        int ng = n0 + wn * 32 + nt * 16 + lr;
        int k = ng >> LOG_DOUT;
        int o = ng & (DOUT - 1);
        float badd = (k == 0) ? bias[o] : 0.f;
#pragma unroll
        for (int r = 0; r < 4; ++r) {
          int m = m0 + wm * 32 + mt * 16 + quad * 4 + r;
          if (m >= N_NODES) continue;
          float val = acc[mt][nt][r] + badd;
          size_t oi = (size_t)m * DOUT + o;
          if (k == 0) {
            y0[oi] = val;
          } else {
            void* yk = (k == 1) ? y1 : (k == 2) ? y2 : y3;
            if (YB) ((bf16_t*)yk)[oi] = (bf16_t)val;
            else    ((float*)yk)[oi]  = val;
          }
        }
      }
  }
}

// ---------------- Propagation: out[c] = sum_e norm*z[row_e] + add[c] ----------
// 2 features per lane. ZBF/ABF: z / add in bf16.
// OMODE: 0 = f32 out, 1 = bf16 out, 2 = bf16 hi/lo pair (outv = hi, outv2 = lo)
// EPI: 0 = none, 1 = dropout(key1), 2 = elu then dropout(key2)
template <int D, int EPI, bool ZBF, bool ABF, int OMODE>
__global__ __launch_bounds__(256) void prop_kernel(
    const void* __restrict__ zv, const void* __restrict__ addv,
    void* __restrict__ outv, void* __restrict__ outv2,
    const int* __restrict__ rptr, const int2* __restrict__ erec,
    uint32_t k0, uint32_t k1) {
  constexpr int LPN = D / 2;        // lanes per node (2 feats/lane)
  constexpr int NPB = 256 / LPN;    // nodes per block
  int lane = threadIdx.x % LPN;
  int nsub = threadIdx.x / LPN;
  int c = blockIdx.x * NPB + nsub;
  if (c >= N_NODES) return;
  int e0 = rptr[c], e1 = rptr[c + 1];
  float a0 = 0.f, a1 = 0.f;

  auto ld = [&](int r) -> float2 {
    if (ZBF) {
      bf16x2 v = ((const bf16x2*)zv)[(size_t)r * LPN + lane];
      return make_float2((float)v.x, (float)v.y);
    } else {
      return ((const float2*)zv)[(size_t)r * LPN + lane];
    }
  };

  int e = e0;
  for (; e + 3 < e1; e += 4) {
    int2 q0 = erec[e], q1 = erec[e + 1], q2 = erec[e + 2], q3 = erec[e + 3];
    float2 v0 = ld(q0.x), v1 = ld(q1.x), v2 = ld(q2.x), v3 = ld(q3.x);
    float w0 = __int_as_float(q0.y), w1 = __int_as_float(q1.y);
    float w2 = __int_as_float(q2.y), w3 = __int_as_float(q3.y);
    a0 = fmaf(w0, v0.x, a0); a1 = fmaf(w0, v0.y, a1);
    a0 = fmaf(w1, v1.x, a0); a1 = fmaf(w1, v1.y, a1);
    a0 = fmaf(w2, v2.x, a0); a1 = fmaf(w2, v2.y, a1);
    a0 = fmaf(w3, v3.x, a0); a1 = fmaf(w3, v3.y, a1);
  }
  for (; e < e1; ++e) {
    int2 q = erec[e];
    float wv = __int_as_float(q.y);
    float2 v = ld(q.x);
    a0 = fmaf(wv, v.x, a0); a1 = fmaf(wv, v.y, a1);
  }

  size_t pidx = (size_t)c * LPN + lane;
  uint32_t fidx = (uint32_t)c * D + 2 * lane;
  float ax, ay;
  if (ABF) {
    bf16x2 av = ((const bf16x2*)addv)[pidx];
    ax = (float)av.x; ay = (float)av.y;
  } else {
    float2 av = ((const float2*)addv)[pidx];
    ax = av.x; ay = av.y;
  }
  float o0 = a0 + ax, o1 = a1 + ay;
  if (EPI == 1) {
    o0 *= drop_scale(fidx, k0, k1);
    o1 *= drop_scale(fidx + 1, k0, k1);
  }
  if (EPI == 2) {
    o0 = (o0 > 0.f) ? o0 : expm1f(o0);
    o1 = (o1 > 0.f) ? o1 : expm1f(o1);
    o0 *= drop_scale(fidx, k0, k1);
    o1 *= drop_scale(fidx + 1, k0, k1);
  }
  if (OMODE == 0) {
    ((float2*)outv)[pidx] = make_float2(o0, o1);
  } else if (OMODE == 1) {
    bf16x2 bv; bv.x = (bf16_t)o0; bv.y = (bf16_t)o1;
    ((bf16x2*)outv)[pidx] = bv;
  } else {
    bf16x2 hv, lv;
    hv.x = (bf16_t)o0; hv.y = (bf16_t)o1;
    lv.x = (bf16_t)(o0 - (float)hv.x);
    lv.y = (bf16_t)(o1 - (float)hv.y);
    ((bf16x2*)outv)[pidx] = hv;
    ((bf16x2*)outv2)[pidx] = lv;
  }
}

// ---------------- Launch ----------------
extern "C" void kernel_launch(void* const* d_in, const int* in_sizes, int n_in,
                              void* d_out, int out_size, void* d_ws, size_t ws_size,
                              hipStream_t stream) {
  const float* x  = (const float*)d_in[0];
  const int*   ei = (const int*)d_in[1];
  const float* W1 = (const float*)d_in[2];
  const float* b1 = (const float*)d_in[3];
  const float* W2 = (const float*)d_in[4];
  const float* b2 = (const float*)d_in[5];
  const float* W3 = (const float*)d_in[6];
  const float* b3 = (const float*)d_in[7];
  float* out = (float*)d_out;

  char* ws = (char*)d_ws;
  size_t off = 0;
  auto alloc = [&](size_t bytes) -> char* {
    char* p = ws + off;
    off += (bytes + 255) & ~(size_t)255;
    return p;
  };
  int*   flag   = (int*)alloc(256);
  int*   deg    = (int*)alloc((size_t)N_NODES * 4);
  int*   cursor = (int*)alloc((size_t)N_NODES * 4);
  float* dis    = (float*)alloc((size_t)N_NODES * 4);
  int*   rptr   = (int*)alloc((size_t)(N_NODES + 1) * 4);
  int*   bsum   = (int*)alloc((size_t)(SCAN_NB + 1) * 4);
  int*   boffs  = (int*)alloc((size_t)(SCAN_NB + 1) * 4);
  int2*  erec   = (int2*)alloc((size_t)N_EDGES * 8);
  bf16_t* Wb1  = (bf16_t*)alloc(65536 * 2);
  bf16_t* Wb2  = (bf16_t*)alloc(32768 * 2);
  bf16_t* Wb3  = (bf16_t*)alloc(4096 * 2);
  float*  R0  = (float*)alloc((size_t)N_NODES * 128 * 4);  // L1 y0/out; L2 y0
  float*  R2  = (float*)alloc((size_t)N_NODES * 16 * 4);   // L3 z0 (f32)
  bf16_t* Zb0 = (bf16_t*)alloc((size_t)N_NODES * 128 * 2);
  bf16_t* Zb1 = (bf16_t*)alloc((size_t)N_NODES * 128 * 2);
  bf16_t* Bb1 = (bf16_t*)alloc((size_t)N_NODES * 128 * 2);
  bf16_t* Bb2 = (bf16_t*)alloc((size_t)N_NODES * 128 * 2);

  hipMemsetAsync(flag, 0, 256, stream);
  hipMemsetAsync(deg, 0, (size_t)N_NODES * 4, stream);
  hipMemsetAsync(cursor, 0, (size_t)N_NODES * 4, stream);

  detect_kernel<<<8, 256, 0, stream>>>(ei, flag);
  deg_kernel<<<(N_EDGES + 255) / 256, 256, 0, stream>>>(ei, flag, deg);
  dis_kernel<<<(N_NODES + 255) / 256, 256, 0, stream>>>(deg, dis);
  bsum_kernel<<<SCAN_NB, 256, 0, stream>>>(deg, bsum);
  bscan_kernel<<<1, 512, 0, stream>>>(bsum, boffs);
  rptr_kernel<<<SCAN_NB, 256, 0, stream>>>(deg, boffs, rptr);
  fill_kernel<<<(N_EDGES + 255) / 256, 256, 0, stream>>>(ei, flag, dis, rptr,
                                                         cursor, erec);
  wcvt_kernel<<<256, 256, 0, stream>>>(W1, W2, W3, Wb1, Wb2, Wb3);

  // JAX partitionable split of key(42)=(0,42): subkey_i = threefry(key; 0, i)
  uint32_t d10, d11, d20, d21;
  threefry2x32(0u, 42u, 0u, 0u, d10, d11);  // dk1
  threefry2x32(0u, 42u, 0u, 1u, d20, d21);  // dk2

  const int MB = (N_NODES + 63) / 64;       // 1563
  const int PB4  = (N_NODES + 3) / 4;       // D=128 (NPB=4)
  const int PB8  = (N_NODES + 7) / 8;       // D=64  (NPB=8)
  const int PB32 = (N_NODES + 31) / 32;     // D=16  (NPB=32)

  // ---- Layer 1 (128 -> 128): Horner out = A(A(A y3 + y2) + y1) + y0 ; dropout1
  matmul_mfma_kernel<128, 7, 8, true, false><<<MB, 256, 0, stream>>>(
      x, nullptr, Wb1, b1, R0, Bb1, Bb2, Zb0);
  prop_kernel<128, 0, true, true, 1><<<PB4, 256, 0, stream>>>(
      Zb0, Bb2, Zb1, nullptr, rptr, erec, 0, 0);
  prop_kernel<128, 0, true, true, 1><<<PB4, 256, 0, stream>>>(
      Zb1, Bb1, Zb0, nullptr, rptr, erec, 0, 0);
  // final hop: dropout, emit hi/lo bf16 pair for layer-2 A (Ah0=Bb2, Al0=Bb1)
  prop_kernel<128, 1, true, false, 2><<<PB4, 256, 0, stream>>>(
      Zb0, R0, Bb2, Bb1, rptr, erec, d10, d11);

  // ---- Layer 2 (128 -> 64): A = (Bb2, Bb1) hi/lo; epilogue: elu + dropout2
  float*  R1f = R0;                                   // f32 64 (R0 dead)
  bf16_t* S0 = Zb0;                                   // bf16 64-dim slots
  bf16_t* S1 = Zb0 + (size_t)N_NODES * 64;
  bf16_t* S2 = Zb1;
  bf16_t* S3 = Zb1 + (size_t)N_NODES * 64;
  matmul_mfma_kernel<128, 6, 4, true, true><<<MB, 256, 0, stream>>>(
      Bb2, Bb1, Wb2, b2, R1f, S2, S3, S0);
  prop_kernel<64, 0, true, true, 1><<<PB8, 256, 0, stream>>>(
      S0, S3, S1, nullptr, rptr, erec, 0, 0);
  prop_kernel<64, 0, true, true, 1><<<PB8, 256, 0, stream>>>(
      S1, S2, S0, nullptr, rptr, erec, 0, 0);
  // final hop: elu+dropout, emit hi/lo for layer-3 A (Ah1=S2, Al1=S3)
  prop_kernel<64, 2, true, false, 2><<<PB8, 256, 0, stream>>>(
      S0, R1f, S2, S3, rptr, erec, d20, d21);

  // ---- Layer 3 (64 -> 16): A = (S2, S3) hi/lo; z1..z3 bf16 (z fits one L2),
  // z0 f32 accumuland; final hop writes d_out f32.
  float*  z0f = R2;
  bf16_t* zb1 = Bb1;
  bf16_t* zb2 = Bb1 + (size_t)N_NODES * 16;
  bf16_t* zb3 = Bb1 + (size_t)N_NODES * 32;
  matmul_mfma_kernel<64, 4, 1, true, true><<<MB, 256, 0, stream>>>(
      S2, S3, Wb3, b3, z0f, zb1, zb2, zb3);
  prop_kernel<16, 0, true, true, 1><<<PB32, 256, 0, stream>>>(
      zb3, zb2, zb2, nullptr, rptr, erec, 0, 0);
  prop_kernel<16, 0, true, true, 1><<<PB32, 256, 0, stream>>>(
      zb2, zb1, zb1, nullptr, rptr, erec, 0, 0);
  prop_kernel<16, 0, true, false, 0><<<PB32, 256, 0, stream>>>(
      zb1, z0f, out, nullptr, rptr, erec, 0, 0);

  (void)in_sizes; (void)n_in; (void)out_size; (void)ws_size;
}

// Round 8
// 743.330 us; speedup vs baseline: 1.1701x; 1.1182x over previous
//
#include <hip/hip_runtime.h>
#include <stdint.h>
#include <math.h>

#define N_NODES 100000
#define N_EDGES 1600000

typedef __bf16 bf16_t;
typedef __attribute__((ext_vector_type(4))) __bf16 bf16x4;
typedef __attribute__((ext_vector_type(8))) __bf16 bf16x8;
typedef __attribute__((ext_vector_type(4))) float f32x4;

__device__ __forceinline__ f32x4 mfma16(bf16x8 a, bf16x8 b, f32x4 c) {
  return __builtin_amdgcn_mfma_f32_16x16x32_bf16(a, b, c, 0, 0, 0);
}

// ---------------- Threefry-2x32 (JAX-compatible) ----------------
__device__ __host__ __forceinline__ uint32_t rotl32(uint32_t v, int d) {
  return (v << d) | (v >> (32 - d));
}

__device__ __host__ __forceinline__ void threefry2x32(uint32_t k0, uint32_t k1,
                                                      uint32_t x0, uint32_t x1,
                                                      uint32_t& o0, uint32_t& o1) {
  uint32_t ks0 = k0, ks1 = k1, ks2 = k0 ^ k1 ^ 0x1BD11BDAu;
  x0 += ks0; x1 += ks1;
#define TF_R(r) { x0 += x1; x1 = rotl32(x1, r); x1 ^= x0; }
  TF_R(13) TF_R(15) TF_R(26) TF_R(6)
  x0 += ks1; x1 += ks2 + 1u;
  TF_R(17) TF_R(29) TF_R(16) TF_R(24)
  x0 += ks2; x1 += ks0 + 2u;
  TF_R(13) TF_R(15) TF_R(26) TF_R(6)
  x0 += ks0; x1 += ks1 + 3u;
  TF_R(17) TF_R(29) TF_R(16) TF_R(24)
  x0 += ks1; x1 += ks2 + 4u;
  TF_R(13) TF_R(15) TF_R(26) TF_R(6)
  x0 += ks2; x1 += ks0 + 5u;
#undef TF_R
  o0 = x0; o1 = x1;
}

// Partitionable-threefry dropout (JAX default): bits = o0^o1 of tf(key; 0, idx)
__device__ __forceinline__ float drop_scale(uint32_t idx, uint32_t k0, uint32_t k1) {
  uint32_t o0, o1;
  threefry2x32(k0, k1, 0u, idx, o0, o1);
  uint32_t bits = o0 ^ o1;
  float u = __uint_as_float((bits >> 9) | 0x3f800000u) - 1.0f;
  return (u < 0.5f) ? 2.0f : 0.0f;
}

// ---------------- Edge dtype detect ----------------
__global__ __launch_bounds__(256) void detect_kernel(const int* __restrict__ ei,
                                                     int* __restrict__ found_nonzero) {
  int idx = blockIdx.x * 256 + threadIdx.x;  // 0..2047
  size_t j = (size_t)idx * 781;              // < 1.6M
  if (ei[2 * j + 1] != 0) atomicOr(found_nonzero, 1);
}

__device__ __forceinline__ int edge_row(const int* ei, bool i32, int e) {
  return i32 ? ei[e] : ei[2 * (size_t)e];
}
__device__ __forceinline__ int edge_col(const int* ei, bool i32, int e) {
  return i32 ? ei[N_EDGES + e] : ei[2 * ((size_t)N_EDGES + (size_t)e)];
}

// ---------------- Graph preprocessing ----------------
__global__ __launch_bounds__(256) void deg_kernel(const int* __restrict__ ei,
                                                  const int* __restrict__ flag,
                                                  int* __restrict__ deg) {
  int e = blockIdx.x * 256 + threadIdx.x;
  if (e < N_EDGES) {
    bool i32 = *flag != 0;
    atomicAdd(&deg[edge_col(ei, i32, e)], 1);
  }
}

__global__ __launch_bounds__(256) void dis_kernel(const int* __restrict__ deg,
                                                  float* __restrict__ dis) {
  int n = blockIdx.x * 256 + threadIdx.x;
  if (n < N_NODES) {
    int d = deg[n];
    dis[n] = (d > 0) ? (1.0f / sqrtf((float)d)) : 0.0f;
  }
}

#define SCAN_NB 391  // ceil(100000/256)
__global__ __launch_bounds__(256) void bsum_kernel(const int* __restrict__ deg,
                                                   int* __restrict__ bsum) {
  __shared__ int sh[256];
  int i = blockIdx.x * 256 + threadIdx.x;
  sh[threadIdx.x] = (i < N_NODES) ? deg[i] : 0;
  __syncthreads();
  for (int ofs = 128; ofs > 0; ofs >>= 1) {
    if (threadIdx.x < ofs) sh[threadIdx.x] += sh[threadIdx.x + ofs];
    __syncthreads();
  }
  if (threadIdx.x == 0) bsum[blockIdx.x] = sh[0];
}

__global__ __launch_bounds__(512) void bscan_kernel(const int* __restrict__ bsum,
                                                    int* __restrict__ boffs) {
  __shared__ int sh[512];
  int t = threadIdx.x;
  int v = (t < SCAN_NB) ? bsum[t] : 0;
  sh[t] = v;
  __syncthreads();
  for (int ofs = 1; ofs < 512; ofs <<= 1) {
    int u = (t >= ofs) ? sh[t - ofs] : 0;
    __syncthreads();
    sh[t] += u;
    __syncthreads();
  }
  if (t < SCAN_NB) boffs[t] = sh[t] - v;  // exclusive
  if (t == 0) boffs[SCAN_NB] = sh[SCAN_NB - 1];
}

__global__ __launch_bounds__(256) void rptr_kernel(const int* __restrict__ deg,
                                                   const int* __restrict__ boffs,
                                                   int* __restrict__ rptr) {
  __shared__ int sh[256];
  int i = blockIdx.x * 256 + threadIdx.x;
  int v = (i < N_NODES) ? deg[i] : 0;
  sh[threadIdx.x] = v;
  __syncthreads();
  for (int ofs = 1; ofs < 256; ofs <<= 1) {
    int u = (threadIdx.x >= ofs) ? sh[threadIdx.x - ofs] : 0;
    __syncthreads();
    sh[threadIdx.x] += u;
    __syncthreads();
  }
  if (i <= N_NODES) rptr[i] = boffs[blockIdx.x] + sh[threadIdx.x] - v;
}

// One packed 8B record per edge: {row, bitcast(norm)} — single scatter line.
__global__ __launch_bounds__(256) void fill_kernel(const int* __restrict__ ei,
                                                   const int* __restrict__ flag,
                                                   const float* __restrict__ dis,
                                                   const int* __restrict__ rptr,
                                                   int* cursor,
                                                   int2* __restrict__ erec) {
  int e = blockIdx.x * 256 + threadIdx.x;
  if (e < N_EDGES) {
    bool i32 = *flag != 0;
    int r = edge_row(ei, i32, e);
    int c = edge_col(ei, i32, e);
    int p = atomicAdd(&cursor[c], 1);
    int idx = rptr[c] + p;
    float nrm = dis[r] * dis[c];
    erec[idx] = make_int2(r, __float_as_int(nrm));
  }
}

// ---------------- Weight pre-conversion f32 -> bf16 ----------------
__global__ __launch_bounds__(256) void wcvt_kernel(
    const float* __restrict__ W1, const float* __restrict__ W2,
    const float* __restrict__ W3,
    bf16_t* __restrict__ Wb1, bf16_t* __restrict__ Wb2,
    bf16_t* __restrict__ Wb3) {
  int i = blockIdx.x * 256 + threadIdx.x;
  if (i < 65536) Wb1[i] = (bf16_t)W1[i];
  if (i < 32768) Wb2[i] = (bf16_t)W2[i];
  if (i < 4096)  Wb3[i] = (bf16_t)W3[i];
}

// ---------------- MFMA matmul: y_k = h @ W_k^T (+bias into y0) ----------------
// OPERAND-SWAPPED: computes D^T = W·h^T, so each thread's 4 acc regs are 4
// CONSECUTIVE OUTPUT FEATURES of one node -> float4/bf16x4 vector stores.
// A/B fragments share the same lane layout for 16x16x32, so the swap is free.
// A = hi+lo bf16 split (exact), W bf16. Node frags hoisted to registers once;
// W double-buffered in the freed staging LDS, pipelined with MFMA.
template <int DIN, int LOG_DOUT, int NCH, bool YB, bool AHL>
__global__ __launch_bounds__(256) void matmul_mfma_kernel(
    const void* __restrict__ hA, const void* __restrict__ hAlo,
    const bf16_t* __restrict__ Wb, const float* __restrict__ bias,
    float* __restrict__ y0, void* __restrict__ y1,
    void* __restrict__ y2, void* __restrict__ y3) {
  constexpr int LDK = DIN + 8;
  constexpr int DOUT = 1 << LOG_DOUT;
  constexpr int KI = DIN / 32;
  __shared__ bf16_t sm[2][64 * LDK];  // A hi/lo staging -> W double-buffer
  const int m0 = blockIdx.x * 64;
  const int tid = threadIdx.x;

  // ---- Stage node tile: hi -> sm[0], lo -> sm[1] ----
  if (AHL) {
    constexpr int NL = 64 * DIN / 8 / 256;  // uint4 = 8 bf16
#pragma unroll
    for (int it = 0; it < NL; ++it) {
      int idx = tid + it * 256;
      int r = idx / (DIN / 8), cc = (idx % (DIN / 8)) * 8;
      int gm = m0 + r;
      uint4 vh = make_uint4(0, 0, 0, 0), vl = make_uint4(0, 0, 0, 0);
      if (gm < N_NODES) {
        vh = ((const uint4*)hA)[((size_t)gm * DIN + cc) >> 3];
        vl = ((const uint4*)hAlo)[((size_t)gm * DIN + cc) >> 3];
      }
      *(uint4*)&sm[0][r * LDK + cc] = vh;
      *(uint4*)&sm[1][r * LDK + cc] = vl;
    }
  } else {
    constexpr int NL = 64 * DIN / 4 / 256;
    union U4 { bf16_t b[4]; uint2 u; };
#pragma unroll
    for (int it = 0; it < NL; ++it) {
      int idx = tid + it * 256;
      int r = idx / (DIN / 4), cc = (idx % (DIN / 4)) * 4;
      int gm = m0 + r;
      float4 v = (gm < N_NODES) ? ((const float4*)hA)[((size_t)gm * DIN + cc) >> 2]
                                : make_float4(0.f, 0.f, 0.f, 0.f);
      U4 hi, lo;
      hi.b[0] = (bf16_t)v.x; lo.b[0] = (bf16_t)(v.x - (float)hi.b[0]);
      hi.b[1] = (bf16_t)v.y; lo.b[1] = (bf16_t)(v.y - (float)hi.b[1]);
      hi.b[2] = (bf16_t)v.z; lo.b[2] = (bf16_t)(v.z - (float)hi.b[2]);
      hi.b[3] = (bf16_t)v.w; lo.b[3] = (bf16_t)(v.w - (float)hi.b[3]);
      *(uint2*)&sm[0][r * LDK + cc] = hi.u;
      *(uint2*)&sm[1][r * LDK + cc] = lo.u;
    }
  }
  __syncthreads();

  const int w = tid >> 6, lane = tid & 63;
  const int wm = w & 1, wn = w >> 1;
  const int quad = lane >> 4, lr = lane & 15;

  // ---- Hoist node fragments to registers (read LDS once) ----
  bf16x8 aH[2][KI], aL[2][KI];
#pragma unroll
  for (int mt = 0; mt < 2; ++mt)
#pragma unroll
    for (int ki = 0; ki < KI; ++ki) {
      int rowa = wm * 32 + mt * 16 + lr;
      int koff = ki * 32 + quad * 8;
      aH[mt][ki] = *(const bf16x8*)&sm[0][rowa * LDK + koff];
      aL[mt][ki] = *(const bf16x8*)&sm[1][rowa * LDK + koff];
    }
  __syncthreads();  // staging LDS now free for W double-buffer

  constexpr int NLB = 64 * DIN / 8 / 256;  // uint4 loads of bf16 W
  uint4 wreg[NLB];
#pragma unroll
  for (int it = 0; it < NLB; ++it) {
    int idx = tid + it * 256;
    int r = idx / (DIN / 8), cc = (idx % (DIN / 8)) * 8;
    wreg[it] = ((const uint4*)Wb)[(((size_t)r) * DIN + cc) >> 3];
    *(uint4*)&sm[0][r * LDK + cc] = wreg[it];
  }
  __syncthreads();

  for (int nc = 0; nc < NCH; ++nc) {
    int p = nc & 1;
    if (nc + 1 < NCH) {
#pragma unroll
      for (int it = 0; it < NLB; ++it) {
        int idx = tid + it * 256;
        int r = idx / (DIN / 8), cc = (idx % (DIN / 8)) * 8;
        wreg[it] = ((const uint4*)Wb)[(((size_t)((nc + 1) * 64 + r)) * DIN + cc) >> 3];
      }
    }

    f32x4 acc[2][2] = {};  // [node-tile][feat-tile]
#pragma unroll
    for (int ki = 0; ki < KI; ++ki) {
      int koff = ki * 32 + quad * 8;
      bf16x8 bfr[2];
#pragma unroll
      for (int nt = 0; nt < 2; ++nt)
        bfr[nt] = *(const bf16x8*)&sm[p][(wn * 32 + nt * 16 + lr) * LDK + koff];
#pragma unroll
      for (int mt = 0; mt < 2; ++mt)
#pragma unroll
        for (int nt = 0; nt < 2; ++nt) {
          // swapped: D^T = W-frag (rows) x node-frag (cols)
          acc[mt][nt] = mfma16(bfr[nt], aH[mt][ki], acc[mt][nt]);
          acc[mt][nt] = mfma16(bfr[nt], aL[mt][ki], acc[mt][nt]);
        }
    }

    if (nc + 1 < NCH) {
#pragma unroll
      for (int it = 0; it < NLB; ++it) {
        int idx = tid + it * 256;
        int r = idx / (DIN / 8), cc = (idx % (DIN / 8)) * 8;
        *(uint4*)&sm[p ^ 1][r * LDK + cc] = wreg[it];
      }
    }
    __syncthreads();

    // ---- Epilogue chunk nc: thread holds node m = wm*32+mt*16+lr,
    //      features n = nc*64 + wn*32 + nt*16 + quad*4 + {0..3} (consecutive).
    const int n0 = nc * 64;
#pragma unroll
    for (int mt = 0; mt < 2; ++mt) {
      int m = m0 + wm * 32 + mt * 16 + lr;
      if (m >= N_NODES) continue;
#pragma unroll
      for (int nt = 0; nt < 2; ++nt) {
        int nb = n0 + wn * 32 + nt * 16 + quad * 4;
        int k = nb >> LOG_DOUT;
        int o = nb & (DOUT - 1);
        size_t oi = (size_t)m * DOUT + o;
        if (k == 0) {
          float4 bv = *(const float4*)&bias[o];
          float4 st = make_float4(acc[mt][nt][0] + bv.x, acc[mt][nt][1] + bv.y,
                                  acc[mt][nt][2] + bv.z, acc[mt][nt][3] + bv.w);
          *(float4*)&y0[oi] = st;
        } else {
          void* yk = (k == 1) ? y1 : (k == 2) ? y2 : y3;
          if (YB) {
            bf16x4 bb;
            bb.x = (bf16_t)acc[mt][nt][0];
            bb.y = (bf16_t)acc[mt][nt][1];
            bb.z = (bf16_t)acc[mt][nt][2];
            bb.w = (bf16_t)acc[mt][nt][3];
            *(bf16x4*)((bf16_t*)yk + oi) = bb;
          } else {
            *(f32x4*)((float*)yk + oi) = acc[mt][nt];
          }
        }
      }
    }
  }
}

// ---------------- Propagation: out[c] = sum_e norm*z[row_e] + add[c] ----------
// 4 features per lane (bf16x4 / float4 loads). ZBF/ABF: z / add in bf16.
// OMODE: 0 = f32 out, 1 = bf16 out, 2 = bf16 hi/lo pair (outv = hi, outv2 = lo)
// EPI: 0 = none, 1 = dropout(key1), 2 = elu then dropout(key2)
template <int D, int EPI, bool ZBF, bool ABF, int OMODE>
__global__ __launch_bounds__(256) void prop_kernel(
    const void* __restrict__ zv, const void* __restrict__ addv,
    void* __restrict__ outv, void* __restrict__ outv2,
    const int* __restrict__ rptr, const int2* __restrict__ erec,
    uint32_t k0, uint32_t k1) {
  constexpr int LPN = D / 4;        // lanes per node (4 feats/lane)
  constexpr int NPB = 256 / LPN;    // nodes per block
  int lane = threadIdx.x % LPN;
  int nsub = threadIdx.x / LPN;
  int c = blockIdx.x * NPB + nsub;
  if (c >= N_NODES) return;
  int e0 = rptr[c], e1 = rptr[c + 1];
  float a0 = 0.f, a1 = 0.f, a2 = 0.f, a3 = 0.f;

  auto ld = [&](int r, float v[4]) {
    if (ZBF) {
      bf16x4 t = ((const bf16x4*)zv)[(size_t)r * LPN + lane];
      v[0] = (float)t.x; v[1] = (float)t.y; v[2] = (float)t.z; v[3] = (float)t.w;
    } else {
      float4 t = ((const float4*)zv)[(size_t)r * LPN + lane];
      v[0] = t.x; v[1] = t.y; v[2] = t.z; v[3] = t.w;
    }
  };

  int e = e0;
  for (; e + 3 < e1; e += 4) {
    int2 q[4];
    float v[4][4];
#pragma unroll
    for (int j = 0; j < 4; ++j) q[j] = erec[e + j];
#pragma unroll
    for (int j = 0; j < 4; ++j) ld(q[j].x, v[j]);
#pragma unroll
    for (int j = 0; j < 4; ++j) {
      float wv = __int_as_float(q[j].y);
      a0 = fmaf(wv, v[j][0], a0);
      a1 = fmaf(wv, v[j][1], a1);
      a2 = fmaf(wv, v[j][2], a2);
      a3 = fmaf(wv, v[j][3], a3);
    }
  }
  for (; e < e1; ++e) {
    int2 q = erec[e];
    float wv = __int_as_float(q.y);
    float v[4];
    ld(q.x, v);
    a0 = fmaf(wv, v[0], a0);
    a1 = fmaf(wv, v[1], a1);
    a2 = fmaf(wv, v[2], a2);
    a3 = fmaf(wv, v[3], a3);
  }

  size_t pidx = (size_t)c * LPN + lane;
  uint32_t fidx = (uint32_t)c * D + 4 * lane;
  float ax[4];
  if (ABF) {
    bf16x4 t = ((const bf16x4*)addv)[pidx];
    ax[0] = (float)t.x; ax[1] = (float)t.y; ax[2] = (float)t.z; ax[3] = (float)t.w;
  } else {
    float4 t = ((const float4*)addv)[pidx];
    ax[0] = t.x; ax[1] = t.y; ax[2] = t.z; ax[3] = t.w;
  }
  float o[4] = {a0 + ax[0], a1 + ax[1], a2 + ax[2], a3 + ax[3]};
  if (EPI == 1) {
#pragma unroll
    for (int j = 0; j < 4; ++j) o[j] *= drop_scale(fidx + j, k0, k1);
  }
  if (EPI == 2) {
#pragma unroll
    for (int j = 0; j < 4; ++j) {
      o[j] = (o[j] > 0.f) ? o[j] : expm1f(o[j]);
      o[j] *= drop_scale(fidx + j, k0, k1);
    }
  }
  if (OMODE == 0) {
    ((float4*)outv)[pidx] = make_float4(o[0], o[1], o[2], o[3]);
  } else if (OMODE == 1) {
    bf16x4 bv;
    bv.x = (bf16_t)o[0]; bv.y = (bf16_t)o[1];
    bv.z = (bf16_t)o[2]; bv.w = (bf16_t)o[3];
    ((bf16x4*)outv)[pidx] = bv;
  } else {
    bf16x4 hv, lv;
    hv.x = (bf16_t)o[0]; hv.y = (bf16_t)o[1];
    hv.z = (bf16_t)o[2]; hv.w = (bf16_t)o[3];
    lv.x = (bf16_t)(o[0] - (float)hv.x);
    lv.y = (bf16_t)(o[1] - (float)hv.y);
    lv.z = (bf16_t)(o[2] - (float)hv.z);
    lv.w = (bf16_t)(o[3] - (float)hv.w);
    ((bf16x4*)outv)[pidx] = hv;
    ((bf16x4*)outv2)[pidx] = lv;
  }
}

// ---------------- Launch ----------------
extern "C" void kernel_launch(void* const* d_in, const int* in_sizes, int n_in,
                              void* d_out, int out_size, void* d_ws, size_t ws_size,
                              hipStream_t stream) {
  const float* x  = (const float*)d_in[0];
  const int*   ei = (const int*)d_in[1];
  const float* W1 = (const float*)d_in[2];
  const float* b1 = (const float*)d_in[3];
  const float* W2 = (const float*)d_in[4];
  const float* b2 = (const float*)d_in[5];
  const float* W3 = (const float*)d_in[6];
  const float* b3 = (const float*)d_in[7];
  float* out = (float*)d_out;

  char* ws = (char*)d_ws;
  size_t off = 0;
  auto alloc = [&](size_t bytes) -> char* {
    char* p = ws + off;
    off += (bytes + 255) & ~(size_t)255;
    return p;
  };
  int*   flag   = (int*)alloc(256);
  int*   deg    = (int*)alloc((size_t)N_NODES * 4);
  int*   cursor = (int*)alloc((size_t)N_NODES * 4);
  float* dis    = (float*)alloc((size_t)N_NODES * 4);
  int*   rptr   = (int*)alloc((size_t)(N_NODES + 1) * 4);
  int*   bsum   = (int*)alloc((size_t)(SCAN_NB + 1) * 4);
  int*   boffs  = (int*)alloc((size_t)(SCAN_NB + 1) * 4);
  int2*  erec   = (int2*)alloc((size_t)N_EDGES * 8);
  bf16_t* Wb1  = (bf16_t*)alloc(65536 * 2);
  bf16_t* Wb2  = (bf16_t*)alloc(32768 * 2);
  bf16_t* Wb3  = (bf16_t*)alloc(4096 * 2);
  float*  R0  = (float*)alloc((size_t)N_NODES * 128 * 4);  // L1 y0/out; L2 y0
  float*  R2  = (float*)alloc((size_t)N_NODES * 16 * 4);   // L3 z0 (f32)
  bf16_t* Zb0 = (bf16_t*)alloc((size_t)N_NODES * 128 * 2);
  bf16_t* Zb1 = (bf16_t*)alloc((size_t)N_NODES * 128 * 2);
  bf16_t* Bb1 = (bf16_t*)alloc((size_t)N_NODES * 128 * 2);
  bf16_t* Bb2 = (bf16_t*)alloc((size_t)N_NODES * 128 * 2);

  hipMemsetAsync(flag, 0, 256, stream);
  hipMemsetAsync(deg, 0, (size_t)N_NODES * 4, stream);
  hipMemsetAsync(cursor, 0, (size_t)N_NODES * 4, stream);

  detect_kernel<<<8, 256, 0, stream>>>(ei, flag);
  deg_kernel<<<(N_EDGES + 255) / 256, 256, 0, stream>>>(ei, flag, deg);
  dis_kernel<<<(N_NODES + 255) / 256, 256, 0, stream>>>(deg, dis);
  bsum_kernel<<<SCAN_NB, 256, 0, stream>>>(deg, bsum);
  bscan_kernel<<<1, 512, 0, stream>>>(bsum, boffs);
  rptr_kernel<<<SCAN_NB, 256, 0, stream>>>(deg, boffs, rptr);
  fill_kernel<<<(N_EDGES + 255) / 256, 256, 0, stream>>>(ei, flag, dis, rptr,
                                                         cursor, erec);
  wcvt_kernel<<<256, 256, 0, stream>>>(W1, W2, W3, Wb1, Wb2, Wb3);

  // JAX partitionable split of key(42)=(0,42): subkey_i = threefry(key; 0, i)
  uint32_t d10, d11, d20, d21;
  threefry2x32(0u, 42u, 0u, 0u, d10, d11);  // dk1
  threefry2x32(0u, 42u, 0u, 1u, d20, d21);  // dk2

  const int MB = (N_NODES + 63) / 64;        // 1563
  const int PB128 = (N_NODES + 7) / 8;       // D=128: LPN=32, NPB=8
  const int PB64n = (N_NODES + 15) / 16;     // D=64:  LPN=16, NPB=16
  const int PB16n = (N_NODES + 63) / 64;     // D=16:  LPN=4,  NPB=64

  // ---- Layer 1 (128 -> 128): Horner out = A(A(A y3 + y2) + y1) + y0 ; dropout1
  matmul_mfma_kernel<128, 7, 8, true, false><<<MB, 256, 0, stream>>>(
      x, nullptr, Wb1, b1, R0, Bb1, Bb2, Zb0);
  prop_kernel<128, 0, true, true, 1><<<PB128, 256, 0, stream>>>(
      Zb0, Bb2, Zb1, nullptr, rptr, erec, 0, 0);
  prop_kernel<128, 0, true, true, 1><<<PB128, 256, 0, stream>>>(
      Zb1, Bb1, Zb0, nullptr, rptr, erec, 0, 0);
  // final hop: dropout, emit hi/lo bf16 pair for layer-2 A (Ah0=Bb2, Al0=Bb1)
  prop_kernel<128, 1, true, false, 2><<<PB128, 256, 0, stream>>>(
      Zb0, R0, Bb2, Bb1, rptr, erec, d10, d11);

  // ---- Layer 2 (128 -> 64): A = (Bb2, Bb1) hi/lo; epilogue: elu + dropout2
  float*  R1f = R0;                                   // f32 64 (R0 dead)
  bf16_t* S0 = Zb0;                                   // bf16 64-dim slots
  bf16_t* S1 = Zb0 + (size_t)N_NODES * 64;
  bf16_t* S2 = Zb1;
  bf16_t* S3 = Zb1 + (size_t)N_NODES * 64;
  matmul_mfma_kernel<128, 6, 4, true, true><<<MB, 256, 0, stream>>>(
      Bb2, Bb1, Wb2, b2, R1f, S2, S3, S0);
  prop_kernel<64, 0, true, true, 1><<<PB64n, 256, 0, stream>>>(
      S0, S3, S1, nullptr, rptr, erec, 0, 0);
  prop_kernel<64, 0, true, true, 1><<<PB64n, 256, 0, stream>>>(
      S1, S2, S0, nullptr, rptr, erec, 0, 0);
  // final hop: elu+dropout, emit hi/lo for layer-3 A (Ah1=S2, Al1=S3)
  prop_kernel<64, 2, true, false, 2><<<PB64n, 256, 0, stream>>>(
      S0, R1f, S2, S3, rptr, erec, d20, d21);

  // ---- Layer 3 (64 -> 16): A = (S2, S3) hi/lo; z1..z3 bf16, z0 f32 accumuland
  float*  z0f = R2;
  bf16_t* zb1 = Bb1;
  bf16_t* zb2 = Bb1 + (size_t)N_NODES * 16;
  bf16_t* zb3 = Bb1 + (size_t)N_NODES * 32;
  matmul_mfma_kernel<64, 4, 1, true, true><<<MB, 256, 0, stream>>>(
      S2, S3, Wb3, b3, z0f, zb1, zb2, zb3);
  prop_kernel<16, 0, true, true, 1><<<PB16n, 256, 0, stream>>>(
      zb3, zb2, zb2, nullptr, rptr, erec, 0, 0);
  prop_kernel<16, 0, true, true, 1><<<PB16n, 256, 0, stream>>>(
      zb2, zb1, zb1, nullptr, rptr, erec, 0, 0);
  prop_kernel<16, 0, true, false, 0><<<PB16n, 256, 0, stream>>>(
      zb1, z0f, out, nullptr, rptr, erec, 0, 0);

  (void)in_sizes; (void)n_in; (void)out_size; (void)ws_size;
}